// Round 1
// baseline (1258.243 us; speedup 1.0000x reference)
//
#include <hip/hip_runtime.h>
#include <stdint.h>

#define T_DIM 2048
#define B_DIM 1024
#define A_DIM 4
#define D_DIM 128
#define TC 32
#define NCHUNK (T_DIM / TC)
#define MROWS (A_DIM * TC)     // 128 GEMM rows per chunk (a*TC + t)
#define NT 9                   // n-tiles: 8 data (128 cols) + 1 kappa tile
#define LDC 144                // LDS row strides (bf16 elems), 144*2B = 288B == 72 dwords == 8 mod 32 banks
#define LDH 144
#define LDQ 144

typedef __attribute__((ext_vector_type(8))) short bf16x8;
typedef __attribute__((ext_vector_type(4))) float f32x4;

__device__ __forceinline__ uint16_t f2bf(float f) {
    uint32_t u = __builtin_bit_cast(uint32_t, f);
    u += 0x7FFFu + ((u >> 16) & 1u);           // RNE
    return (uint16_t)(u >> 16);
}
__device__ __forceinline__ float bf2f(uint16_t h) {
    uint32_t u = ((uint32_t)h) << 16;
    return __builtin_bit_cast(float, u);
}
__device__ __forceinline__ uint32_t packbf2(float a, float b) {
    return (uint32_t)f2bf(a) | ((uint32_t)f2bf(b) << 16);
}
__device__ __forceinline__ float clampf(float x, float lo, float hi) {
    return fminf(fmaxf(x, lo), hi);
}

// One block per b (1024 blocks, 256 threads = 4 waves).
// Phase 0: gather+clip C[pid] transposed to LDS bf16 (B-operand layout), params.
// Per chunk of 32 steps: fp32 elementwise scan writes H,Q (bf16) to LDS;
// MFMA GEMM G = H x C (M=128,N=144,K=128); epilogue logit = sum_n (G+beta)*Q.
__global__ __launch_bounds__(256, 1)
void gql_fused(const float* __restrict__ inp,
               const float* __restrict__ phi_raw,
               const float* __restrict__ chi_raw,
               const float* __restrict__ beta_raw,
               const float* __restrict__ kappa_raw,
               const float* __restrict__ C_raw,
               float* __restrict__ out)
{
    __shared__ uint16_t Ct[NT * 16 * LDC];   // Ct[n][k] = bf16(clip(C[k][n])); row128=kappa, 129..143=0
    __shared__ uint16_t Hb[MROWS * LDH];     // Hb[m][k] bf16, m = a*TC + t
    __shared__ uint16_t Qb[MROWS * LDQ];     // Qb[m][n] bf16; col128=1.0, 129..143=0
    __shared__ float    xb[2][TC][9];        // staged inputs (double buffer)
    __shared__ float    betas[NT * 16];      // clip(softplus(beta)); 128..143 = 0

    const int b    = blockIdx.x;
    const int tid  = threadIdx.x;
    const int lane = tid & 63;
    const int wv   = tid >> 6;      // wave id == action owned in the scan
    const int ml   = lane & 15;
    const int qd   = lane >> 4;

    const int pid = (int)inp[(size_t)b * 9 + 8];    // x[0, b, 8]

    // ---- per-thread scan params: this thread owns (a=wv, d0=2*lane, d0+1)
    const int d0 = lane * 2;
    float2 pr = *(const float2*)(phi_raw + (size_t)pid * D_DIM + d0);
    float2 cr = *(const float2*)(chi_raw + (size_t)pid * D_DIM + d0);
    float phi0 = clampf(1.f / (1.f + __expf(-pr.x)), 0.01f, 0.99f);
    float phi1 = clampf(1.f / (1.f + __expf(-pr.y)), 0.01f, 0.99f);
    float chi0 = clampf(1.f / (1.f + __expf(-cr.x)), 0.01f, 0.99f);
    float chi1 = clampf(1.f / (1.f + __expf(-cr.y)), 0.01f, 0.99f);
    float omphi0 = 1.f - phi0, omphi1 = 1.f - phi1;
    float omchi0 = 1.f - chi0, omchi1 = 1.f - chi1;

    // ---- stage C[pid] transposed, clipped, bf16
    const float* Cp = C_raw + (size_t)pid * (D_DIM * D_DIM);
    #pragma unroll 8
    for (int i = 0; i < 64; ++i) {
        int idx = i * 256 + tid;            // idx = d*128 + e
        int d = idx >> 7, e = idx & 127;
        Ct[e * LDC + d] = f2bf(clampf(Cp[idx], -10.f, 10.f));
    }
    // kappa row (n=128) + zero rows 129..143
    for (int i = tid; i < 16 * LDC; i += 256) {
        int n = i / LDC;
        int k = i - n * LDC;
        float v = 0.f;
        if (n == 0 && k < D_DIM) v = clampf(kappa_raw[(size_t)pid * D_DIM + k], -10.f, 10.f);
        Ct[(128 + n) * LDC + k] = f2bf(v);
    }
    // betas
    for (int i = tid; i < NT * 16; i += 256) {
        float v = 0.f;
        if (i < D_DIM) {
            float x = beta_raw[(size_t)pid * D_DIM + i];
            v = clampf(log1pf(__expf(x)), 0.1f, 10.f);
        }
        betas[i] = v;
    }
    // Qb constant columns 128..143 (1,0,0,...)
    for (int i = tid; i < MROWS * 16; i += 256) {
        int m = i >> 4, c = i & 15;
        Qb[m * LDQ + 128 + c] = (c == 0) ? (uint16_t)0x3F80 : (uint16_t)0;
    }

    // ---- input staging helper: i in [0,288) -> x[chunk*TC + i/9, b, i%9]
    auto ldx = [&](int i, int chunk) -> float {
        int tl = i / 9, c = i - tl * 9;
        float v = inp[((size_t)(chunk * TC + tl) * B_DIM + b) * 9 + c];
        return (v == v) ? v : 0.f;          // nan_to_num
    };
    {
        float v0 = ldx(tid, 0);
        float v1 = (tid < 32) ? ldx(256 + tid, 0) : 0.f;
        int tl0 = tid / 9, c0 = tid - tl0 * 9;
        xb[0][tl0][c0] = v0;
        if (tid < 32) { int i = 256 + tid; xb[0][i / 9][i % 9] = v1; }
    }
    __syncthreads();

    float breg[NT];
    #pragma unroll
    for (int nt = 0; nt < NT; ++nt) breg[nt] = betas[nt * 16 + ml];

    float q0 = 0.5f, q1 = 0.5f, h0 = 0.f, h1 = 0.f;

    for (int chunk = 0; chunk < NCHUNK; ++chunk) {
        const int cur = chunk & 1;
        // prefetch next chunk's inputs into registers (latency hidden by scan+GEMM)
        float nv0 = 0.f, nv1 = 0.f;
        if (chunk + 1 < NCHUNK) {
            nv0 = ldx(tid, chunk + 1);
            if (tid < 32) nv1 = ldx(256 + tid, chunk + 1);
        }

        // ---- scan: 32 steps, no inter-thread deps, no barriers
        #pragma unroll
        for (int tl = 0; tl < TC; ++tl) {
            float act = xb[cur][tl][wv];
            float rr  = xb[cur][tl][4 + wv];
            float ra  = rr * act;
            q0 = omphi0 * q0 + phi0 * ra;
            q1 = omphi1 * q1 + phi1 * ra;
            h0 = omchi0 * h0 + chi0 * act;
            h1 = omchi1 * h1 + chi1 * act;
            int m = wv * TC + tl;
            *(uint32_t*)&Hb[m * LDH + d0] = packbf2(h0, h1);
            *(uint32_t*)&Qb[m * LDQ + d0] = packbf2(q0, q1);
        }
        __syncthreads();

        // ---- GEMM: wave wv owns m-tiles {2wv, 2wv+1}, all 9 n-tiles, K=128
        f32x4 acc[2][NT];
        #pragma unroll
        for (int mi = 0; mi < 2; ++mi)
            #pragma unroll
            for (int nt = 0; nt < NT; ++nt)
                acc[mi][nt] = (f32x4){0.f, 0.f, 0.f, 0.f};

        #pragma unroll
        for (int kt = 0; kt < 4; ++kt) {
            const int kb = kt * 32 + qd * 8;
            bf16x8 bfr[NT];
            #pragma unroll
            for (int nt = 0; nt < NT; ++nt)
                bfr[nt] = *(const bf16x8*)&Ct[(nt * 16 + ml) * LDC + kb];
            #pragma unroll
            for (int mi = 0; mi < 2; ++mi) {
                bf16x8 afr = *(const bf16x8*)&Hb[((wv * 2 + mi) * 16 + ml) * LDH + kb];
                #pragma unroll
                for (int nt = 0; nt < NT; ++nt)
                    acc[mi][nt] = __builtin_amdgcn_mfma_f32_16x16x32_bf16(afr, bfr[nt], acc[mi][nt], 0, 0, 0);
            }
        }

        // ---- epilogue: logit[m] = sum_n (G[m,n]+beta[n]) * Qb[m,n]  (n=128 col picks kappa·h)
        #pragma unroll
        for (int mi = 0; mi < 2; ++mi) {
            const int mt = wv * 2 + mi;
            float pl[4];
            #pragma unroll
            for (int r4 = 0; r4 < 4; ++r4) {
                int row = mt * 16 + qd * 4 + r4;
                float p = 0.f;
                #pragma unroll
                for (int nt = 0; nt < NT; ++nt) {
                    float qv = bf2f(Qb[row * LDQ + nt * 16 + ml]);
                    p += (acc[mi][nt][r4] + breg[nt]) * qv;
                }
                pl[r4] = p;
            }
            #pragma unroll
            for (int off = 1; off < 16; off <<= 1) {
                #pragma unroll
                for (int r4 = 0; r4 < 4; ++r4)
                    pl[r4] += __shfl_xor(pl[r4], off, 64);
            }
            if (ml == 0) {
                #pragma unroll
                for (int r4 = 0; r4 < 4; ++r4) {
                    int row = mt * 16 + qd * 4 + r4;
                    int aa = row >> 5;           // row / TC
                    int tl = row & (TC - 1);
                    size_t t = (size_t)chunk * TC + tl;
                    out[(t * B_DIM + b) * A_DIM + aa] = pl[r4];
                }
            }
        }

        // commit staged inputs for next chunk
        if (chunk + 1 < NCHUNK) {
            int tl0 = tid / 9, c0 = tid - tl0 * 9;
            xb[cur ^ 1][tl0][c0] = nv0;
            if (tid < 32) { int i = 256 + tid; xb[cur ^ 1][i / 9][i % 9] = nv1; }
        }
        __syncthreads();
    }

    // ---- final q, h outputs (fp32 state, exact recurrence)
    size_t qbase = (size_t)T_DIM * B_DIM * A_DIM;
    size_t off = (size_t)b * (A_DIM * D_DIM) + (size_t)wv * D_DIM + d0;
    *(float2*)&out[qbase + off] = make_float2(q0, q1);
    *(float2*)&out[qbase + (size_t)B_DIM * A_DIM * D_DIM + off] = make_float2(h0, h1);
}

extern "C" void kernel_launch(void* const* d_in, const int* in_sizes, int n_in,
                              void* d_out, int out_size, void* d_ws, size_t ws_size,
                              hipStream_t stream) {
    const float* inp    = (const float*)d_in[0];
    const float* phi_r  = (const float*)d_in[1];
    const float* chi_r  = (const float*)d_in[2];
    const float* beta_r = (const float*)d_in[3];
    const float* kap_r  = (const float*)d_in[4];
    const float* C_r    = (const float*)d_in[5];
    float* outp = (float*)d_out;
    gql_fused<<<dim3(B_DIM), dim3(256), 0, stream>>>(inp, phi_r, chi_r, beta_r, kap_r, C_r, outp);
}

// Round 2
// 610.031 us; speedup vs baseline: 2.0626x; 2.0626x over previous
//
#include <hip/hip_runtime.h>
#include <stdint.h>

#define T_DIM 2048
#define B_DIM 1024
#define A_DIM 4
#define D_DIM 128
#define TC 32
#define NCHUNK (T_DIM / TC)
#define LDH 136                 // Hb row stride in bf16 elems (68 dwords == 4 mod 32 -> conflict-free b128)
#define LDC 136                 // Ct staging row stride
#define HB_BYTES (128 * LDH * 2)        // 34816
#define QT_S 65                 // Qt col stride in dwords
#define SMEM_BYTES (HB_BYTES + 128 * QT_S * 4)   // 34816 + 33280 = 68096 (<80KB -> 2 blocks/CU)

typedef __attribute__((ext_vector_type(8))) short bf16x8;
typedef __attribute__((ext_vector_type(4))) float f32x4;

__device__ __forceinline__ float clampf(float x, float lo, float hi) {
    return fminf(fmaxf(x, lo), hi);
}
__device__ __forceinline__ uint16_t bf16rnd(float f) {
    uint32_t u = __builtin_bit_cast(uint32_t, f) + 0x8000u;   // round-nearest (ties away)
    return (uint16_t)(u >> 16);
}
// pack2(x,y) -> (bf16(y)<<16)|bf16(x) in 3 VALU ops
__device__ __forceinline__ uint32_t pack2(float x, float y) {
    uint32_t ux = __builtin_bit_cast(uint32_t, x) + 0x8000u;
    uint32_t uy = __builtin_bit_cast(uint32_t, y) + 0x8000u;
    return __builtin_amdgcn_perm(uy, ux, 0x07060302);
}
__device__ __forceinline__ float bfLO(uint32_t u) {
    return __builtin_bit_cast(float, u << 16);
}
__device__ __forceinline__ float bfHI(uint32_t u) {
    return __builtin_bit_cast(float, u & 0xFFFF0000u);
}
template <int CTRL>
__device__ __forceinline__ float dppadd(float x) {
    int xi = __builtin_bit_cast(int, x);
    int yi = __builtin_amdgcn_mov_dpp(xi, CTRL, 0xF, 0xF, false);
    return x + __builtin_bit_cast(float, yi);
}
// sum across the 16 lanes of each DPP row (our ml-groups) via row_ror 1,2,4,8
__device__ __forceinline__ float rowsum16(float x) {
    x = dppadd<0x121>(x);
    x = dppadd<0x122>(x);
    x = dppadd<0x124>(x);
    x = dppadd<0x128>(x);
    return x;
}

// One block per b; 4 waves; wave wv owns action a=wv. No main-loop barriers:
// each wave only touches its own 32 rows of Hb/Qt. Ct (B-fragments) lives in
// registers (144 VGPRs), loaded once from an LDS staging area that is then
// overlaid by Hb/Qt. 66.5 KB LDS + <=256 VGPR -> 2 blocks/CU.
__global__ __launch_bounds__(256, 2)
void gql_fused(const float* __restrict__ inp,
               const float* __restrict__ phi_raw,
               const float* __restrict__ chi_raw,
               const float* __restrict__ beta_raw,
               const float* __restrict__ kappa_raw,
               const float* __restrict__ C_raw,
               float* __restrict__ out)
{
    __shared__ __attribute__((aligned(16))) char smem[SMEM_BYTES];

    const int b    = blockIdx.x;
    const int tid  = threadIdx.x;
    const int lane = tid & 63;
    const int wv   = tid >> 6;
    const int ml   = lane & 15;
    const int qd   = lane >> 4;

    const int pid = (int)inp[(size_t)b * 9 + 8];

    // ---- scan params: thread owns (a=wv, d0=2*lane, d0+1)
    const int d0 = lane * 2;
    float2 pr = *(const float2*)(phi_raw + (size_t)pid * D_DIM + d0);
    float2 cr = *(const float2*)(chi_raw + (size_t)pid * D_DIM + d0);
    float phi0 = clampf(1.f / (1.f + __expf(-pr.x)), 0.01f, 0.99f);
    float phi1 = clampf(1.f / (1.f + __expf(-pr.y)), 0.01f, 0.99f);
    float chi0 = clampf(1.f / (1.f + __expf(-cr.x)), 0.01f, 0.99f);
    float chi1 = clampf(1.f / (1.f + __expf(-cr.y)), 0.01f, 0.99f);
    float omphi0 = 1.f - phi0, omphi1 = 1.f - phi1;
    float omchi0 = 1.f - chi0, omchi1 = 1.f - chi1;

    // ---- betas in registers (nt<8 real, nt=8 kappa-tile -> 0)
    float breg[9];
    #pragma unroll
    for (int nt = 0; nt < 8; ++nt) {
        float x = beta_raw[(size_t)pid * D_DIM + nt * 16 + ml];
        breg[nt] = clampf(log1pf(__expf(x)), 0.1f, 10.0f);
    }
    breg[8] = 0.f;

    // ---- stage Ct[n][k] = bf16(clip(C[k][n])) into LDS (temporary)
    {
        uint16_t* Ct = (uint16_t*)smem;
        const float* Cp = C_raw + (size_t)pid * (D_DIM * D_DIM);
        #pragma unroll 8
        for (int i = 0; i < 64; ++i) {
            int idx = i * 256 + tid;
            int d = idx >> 7, e = idx & 127;
            Ct[e * LDC + d] = bf16rnd(clampf(Cp[idx], -10.f, 10.f));
        }
        for (int i = tid; i < 16 * LDC; i += 256) {
            int n = i / LDC;
            int k = i - n * LDC;
            float v = (n == 0 && k < D_DIM)
                        ? clampf(kappa_raw[(size_t)pid * D_DIM + k], -10.f, 10.f) : 0.f;
            Ct[(128 + n) * LDC + k] = bf16rnd(v);
        }
    }
    __syncthreads();

    // ---- B-fragments to registers (chunk-invariant): bfr[nt][kt]
    bf16x8 bfr[9][4];
    {
        const uint16_t* Ct = (const uint16_t*)smem;
        #pragma unroll
        for (int nt = 0; nt < 9; ++nt)
            #pragma unroll
            for (int kt = 0; kt < 4; ++kt)
                bfr[nt][kt] = *(const bf16x8*)&Ct[(nt * 16 + ml) * LDC + kt * 32 + qd * 8];
    }
    __syncthreads();   // staging area now dead; reuse as Hb/Qt

    uint32_t* H32 = (uint32_t*)smem;                    // Hb[m][k] bf16-pairs, dword idx m*68+dpair
    uint32_t* Qt  = (uint32_t*)(smem + HB_BYTES);       // Qt col-major: dword(col,m2)=col*65+(m2^SW(col))
    const uint16_t* Hb16 = (const uint16_t*)smem;
    const int SWt = ((lane >> 4) & 3) << 3;             // SW(col=2*lane) == SW(2*lane+1)

    // ---- per-chunk wave-uniform inputs via readlane: lane l<32 holds step l
    float actv, rav;
    {
        size_t t = (size_t)(lane & 31);
        const float* p = inp + (t * B_DIM + b) * 9;
        float a = p[wv], r = p[4 + wv];
        actv = a; rav = a * r;
    }

    float q0 = 0.5f, q1 = 0.5f, h0 = 0.f, h1 = 0.f;

    for (int chunk = 0; chunk < NCHUNK; ++chunk) {
        const int ai = __builtin_bit_cast(int, actv);
        const int ri = __builtin_bit_cast(int, rav);

        // ---- scan: 32 steps, register-only except paired LDS stores
        uint32_t hw_prev = 0, qwA0 = 0, qwA1 = 0;
        float q0p = 0.f, q1p = 0.f;
        #pragma unroll
        for (int tl = 0; tl < TC; ++tl) {
            float sa = __builtin_bit_cast(float, __builtin_amdgcn_readlane(ai, tl));
            float sr = __builtin_bit_cast(float, __builtin_amdgcn_readlane(ri, tl));
            q0 = fmaf(omphi0, q0, phi0 * sr);
            q1 = fmaf(omphi1, q1, phi1 * sr);
            h0 = fmaf(omchi0, h0, chi0 * sa);
            h1 = fmaf(omchi1, h1, chi1 * sa);
            uint32_t hw = pack2(h0, h1);
            if (tl & 1) {
                int m = wv * TC + tl - 1;
                H32[m * 68 + lane] = hw_prev;           // rows m, m+1: ds_write2-mergeable
                H32[(m + 1) * 68 + lane] = hw;
            } else {
                hw_prev = hw;
            }
            if ((tl & 1) == 0) {
                q0p = q0; q1p = q1;
            } else if ((tl & 3) == 1) {
                qwA0 = pack2(q0p, q0);                  // col d0, rows tl-1,tl
                qwA1 = pack2(q1p, q1);                  // col d0+1
            } else {                                    // tl&3 == 3
                uint32_t qwB0 = pack2(q0p, q0);
                uint32_t qwB1 = pack2(q1p, q1);
                int m2  = wv * 16 + ((tl - 3) >> 1);    // even
                int adw = d0 * QT_S + (m2 ^ SWt);
                Qt[adw]     = qwA0;  Qt[adw + 1]        = qwB0;
                Qt[adw + QT_S] = qwA1; Qt[adw + QT_S + 1] = qwB1;
            }
        }

        // prefetch next chunk's inputs (latency hidden behind GEMM+epilogue)
        if (chunk + 1 < NCHUNK) {
            size_t t = (size_t)(chunk + 1) * TC + (lane & 31);
            const float* p = inp + (t * B_DIM + b) * 9;
            float a = p[wv], r = p[4 + wv];
            actv = a; rav = a * r;
        }

        // ---- GEMM + epilogue, one 16-row m-tile at a time (acc regs halved)
        #pragma unroll
        for (int mi = 0; mi < 2; ++mi) {
            const int mt = wv * 2 + mi;
            f32x4 acc[9];
            #pragma unroll
            for (int nt = 0; nt < 9; ++nt) acc[nt] = (f32x4){0.f, 0.f, 0.f, 0.f};

            #pragma unroll
            for (int kt = 0; kt < 4; ++kt) {
                bf16x8 afr = *(const bf16x8*)&Hb16[(size_t)(mt * 16 + ml) * LDH + kt * 32 + qd * 8];
                #pragma unroll
                for (int nt = 0; nt < 9; ++nt)
                    acc[nt] = __builtin_amdgcn_mfma_f32_16x16x32_bf16(afr, bfr[nt][kt], acc[nt], 0, 0, 0);
            }

            // kappa tile: col 128 lives at nt=8, ml==0; Q there == 1, beta == 0
            bool km = (ml == 0);
            float p0 = km ? acc[8][0] : 0.f;
            float p1 = km ? acc[8][1] : 0.f;
            float p2 = km ? acc[8][2] : 0.f;
            float p3 = km ? acc[8][3] : 0.f;

            const int m2e = mt * 8 + qd * 2;            // global m2 of rows row0,row0+1
            #pragma unroll
            for (int nt = 0; nt < 8; ++nt) {
                const int SWc = ((nt >> 1) & 3) << 3;   // SW(col=16nt+ml), ml<16
                int adw = (nt * 16 + ml) * QT_S + (m2e ^ SWc);
                uint32_t w0 = Qt[adw];
                uint32_t w1 = Qt[adw + 1];
                float g0 = acc[nt][0] + breg[nt];
                float g1 = acc[nt][1] + breg[nt];
                float g2 = acc[nt][2] + breg[nt];
                float g3 = acc[nt][3] + breg[nt];
                p0 = fmaf(g0, bfLO(w0), p0);
                p1 = fmaf(g1, bfHI(w0), p1);
                p2 = fmaf(g2, bfLO(w1), p2);
                p3 = fmaf(g3, bfHI(w1), p3);
            }

            p0 = rowsum16(p0);
            p1 = rowsum16(p1);
            p2 = rowsum16(p2);
            p3 = rowsum16(p3);

            if (ml == 0) {
                int row0 = mt * 16 + qd * 4;
                #pragma unroll
                for (int r = 0; r < 4; ++r) {
                    int row = row0 + r;
                    int aa = row >> 5;
                    int tl = row & (TC - 1);
                    size_t t = (size_t)chunk * TC + tl;
                    float pv = (r == 0) ? p0 : (r == 1) ? p1 : (r == 2) ? p2 : p3;
                    out[(t * B_DIM + b) * A_DIM + aa] = pv;
                }
            }
        }
        // no barrier: next scan overwrites only this wave's own rows after its own reads
    }

    // ---- final q, h (fp32 state, exact recurrence)
    size_t qbase = (size_t)T_DIM * B_DIM * A_DIM;
    size_t off = (size_t)b * (A_DIM * D_DIM) + (size_t)wv * D_DIM + d0;
    *(float2*)&out[qbase + off] = make_float2(q0, q1);
    *(float2*)&out[qbase + (size_t)B_DIM * A_DIM * D_DIM + off] = make_float2(h0, h1);
}

extern "C" void kernel_launch(void* const* d_in, const int* in_sizes, int n_in,
                              void* d_out, int out_size, void* d_ws, size_t ws_size,
                              hipStream_t stream) {
    const float* inp    = (const float*)d_in[0];
    const float* phi_r  = (const float*)d_in[1];
    const float* chi_r  = (const float*)d_in[2];
    const float* beta_r = (const float*)d_in[3];
    const float* kap_r  = (const float*)d_in[4];
    const float* C_r    = (const float*)d_in[5];
    float* outp = (float*)d_out;
    gql_fused<<<dim3(B_DIM), dim3(256), 0, stream>>>(inp, phi_r, chi_r, beta_r, kap_r, C_r, outp);
}